// Round 1
// baseline (311.243 us; speedup 1.0000x reference)
//
#include <hip/hip_runtime.h>

#define BATCH 4096
#define NN 128
#define FF 64
#define NC 129          // possible count values 0..128
#define HIST 1000       // ids are randint(0, 1000)
#define PADDED_ID (-1)

// table[c][g] = b2[g] + sum_f relu(c*w1[f] + b1[f]) * w2[g*F + f]
__global__ void build_table_kernel(const float* __restrict__ w1,
                                   const float* __restrict__ b1,
                                   const float* __restrict__ w2,
                                   const float* __restrict__ b2,
                                   float* __restrict__ table) {
    int c = blockIdx.x;        // 0..128
    int g = threadIdx.x;       // 0..63
    float cf = (float)c;
    float acc = b2[g];
    #pragma unroll
    for (int f = 0; f < FF; ++f) {
        float h = cf * w1[f] + b1[f];
        h = h > 0.0f ? h : 0.0f;
        acc += h * w2[g * FF + f];
    }
    table[c * FF + g] = acc;
}

// One block per batch. LDS ~5 KB -> 8 blocks/CU (wave cap).
// R5 theory: emit loop was 3 VMEM instrs per 16B stored (2 table gathers +
// 1 store) -> ~196K VMEM instrs/CU, saturating the CU's vector-memory issue
// pipe (fill kernel hits 6.58 TB/s with stores alone at ~0.67/cy/CU).
// Counts are Binomial(128,1e-3): P(c>=4) ~ 1e-5. Hoist table rows 0..3 into
// registers; per-store gathers become v_cndmask selects (VALU is ~free);
// rare c>3 path falls back to the global gather (correct for any count).
__global__ __launch_bounds__(256, 8)
void encode_kernel(const int* __restrict__ src,
                   const int* __restrict__ dst,
                   const float* __restrict__ table,
                   float* __restrict__ out) {
    __shared__ unsigned s_hist[HIST];   // low16 = count in src, high16 = count in dst
    __shared__ unsigned s_cnt[2 * NN];  // per-row packed (cnt_in_src | cnt_in_dst<<16)

    const int b   = blockIdx.x;
    const int tid = threadIdx.x;

    // threads 0..127 own src rows, 128..255 own dst rows (coalesced id loads)
    const int my = (tid < NN) ? src[b * NN + tid] : dst[b * NN + (tid - NN)];
    const unsigned inc = (tid < NN) ? 1u : 0x10000u;
    const bool valid = (my >= 0) && (my < HIST);

    #pragma unroll
    for (int i = tid; i < HIST; i += 256) s_hist[i] = 0u;
    __syncthreads();

    if (valid) atomicAdd(&s_hist[my], inc);
    __syncthreads();

    // src row: low=src_in_src, high=src_in_dst; dst row: low=dst_in_src, high=dst_in_dst.
    // Emit computes table[lo]+table[hi] -- symmetric in (lo,hi).
    s_cnt[tid] = valid ? s_hist[my] : 0u;
    __syncthreads();

    // ---- emit: out_row = table[c0] + table[c1]; each wave stores 1 KB contiguous ----
    const int g4 = tid & 15;        // float4 lane within a 64-float row
    const int n0 = tid >> 4;        // 0..15
    const float4* __restrict__ tab4 = (const float4*)table;

    // Hot table rows 0..3 live in registers (16 VGPRs): kills the 2 VMEM
    // gathers per store in ~all cases.
    const float4 t0 = tab4[0 * (FF / 4) + g4];
    const float4 t1 = tab4[1 * (FF / 4) + g4];
    const float4 t2 = tab4[2 * (FF / 4) + g4];
    const float4 t3 = tab4[3 * (FF / 4) + g4];

    float4* out_src = (float4*)out + (size_t)b * (NN * FF / 4);
    float4* out_dst = out_src + (size_t)BATCH * (NN * FF / 4);

    #pragma unroll
    for (int n = n0; n < NN; n += 16) {
        {
            const unsigned h  = s_cnt[n];
            const unsigned c0 = h & 0xffffu;
            const unsigned c1 = h >> 16;
            float4 v0 = (c0 == 0u) ? t0 : (c0 == 1u) ? t1 : (c0 == 2u) ? t2 : t3;
            float4 v1 = (c1 == 0u) ? t0 : (c1 == 1u) ? t1 : (c1 == 2u) ? t2 : t3;
            if (__builtin_expect((h & 0xfffcfffcu) != 0u, 0)) {
                // some count > 3: take the exact gather (also correct for <=3)
                v0 = tab4[c0 * (FF / 4) + g4];
                v1 = tab4[c1 * (FF / 4) + g4];
            }
            float4 r;
            r.x = v0.x + v1.x; r.y = v0.y + v1.y;
            r.z = v0.z + v1.z; r.w = v0.w + v1.w;
            out_src[n * (FF / 4) + g4] = r;
        }
        {
            const unsigned h  = s_cnt[NN + n];
            const unsigned c0 = h & 0xffffu;
            const unsigned c1 = h >> 16;
            float4 v0 = (c0 == 0u) ? t0 : (c0 == 1u) ? t1 : (c0 == 2u) ? t2 : t3;
            float4 v1 = (c1 == 0u) ? t0 : (c1 == 1u) ? t1 : (c1 == 2u) ? t2 : t3;
            if (__builtin_expect((h & 0xfffcfffcu) != 0u, 0)) {
                v0 = tab4[c0 * (FF / 4) + g4];
                v1 = tab4[c1 * (FF / 4) + g4];
            }
            float4 r;
            r.x = v0.x + v1.x; r.y = v0.y + v1.y;
            r.z = v0.z + v1.z; r.w = v0.w + v1.w;
            out_dst[n * (FF / 4) + g4] = r;
        }
    }
}

extern "C" void kernel_launch(void* const* d_in, const int* in_sizes, int n_in,
                              void* d_out, int out_size, void* d_ws, size_t ws_size,
                              hipStream_t stream) {
    const int*   src = (const int*)d_in[0];
    const int*   dst = (const int*)d_in[1];
    const float* w1  = (const float*)d_in[2];
    const float* b1  = (const float*)d_in[3];
    const float* w2  = (const float*)d_in[4];
    const float* b2  = (const float*)d_in[5];
    float* out   = (float*)d_out;
    float* table = (float*)d_ws;   // 129*64*4 = 33,024 bytes

    build_table_kernel<<<NC, FF, 0, stream>>>(w1, b1, w2, b2, table);
    encode_kernel<<<BATCH, 256, 0, stream>>>(src, dst, table, out);
}

// Round 2
// 272.927 us; speedup vs baseline: 1.1404x; 1.1404x over previous
//
#include <hip/hip_runtime.h>

#define BATCH 4096
#define NN 128
#define FF 64
#define NC 129          // possible count values 0..128
#define HIST 1000       // ids are randint(0, 1000)
#define NTAB 16         // table rows staged in LDS; counts >= 16 are ~impossible
#define PADDED_ID (-1)

// table[c][g] = b2[g] + sum_f relu(c*w1[f] + b1[f]) * w2[g*F + f]
__global__ void build_table_kernel(const float* __restrict__ w1,
                                   const float* __restrict__ b1,
                                   const float* __restrict__ w2,
                                   const float* __restrict__ b2,
                                   float* __restrict__ table) {
    int c = blockIdx.x;        // 0..128
    int g = threadIdx.x;       // 0..63
    float cf = (float)c;
    float acc = b2[g];
    #pragma unroll
    for (int f = 0; f < FF; ++f) {
        float h = cf * w1[f] + b1[f];
        h = h > 0.0f ? h : 0.0f;
        acc += h * w2[g * FF + f];
    }
    table[c * FF + g] = acc;
}

// One block per batch. LDS ~9 KB -> 8 blocks/CU (wave cap, 32 waves).
// R2 theory: R0's emit loop issued 3 VMEM instrs per 16B stored (2 table
// gathers + 1 store) -> ~196K VMEM instrs/CU; the gathers ride the same
// vector-memory issue pipe as the stores. R1's register-hoist variant risked
// scratch spills under the 64-VGPR cap of __launch_bounds__(256,8).
// This version stages table rows 0..15 (4 KB) in LDS: gathers become
// ds_read_b128 (lgkmcnt pipe, no VMEM slot, ~no bank conflicts since lanes
// mostly read the same row = free 2-way aliasing), zero extra VGPRs.
// Rare counts >= 16 (P ~ 1e-14) fall back to the exact global gather.
__global__ __launch_bounds__(256, 8)
void encode_kernel(const int* __restrict__ src,
                   const int* __restrict__ dst,
                   const float* __restrict__ table,
                   float* __restrict__ out) {
    __shared__ unsigned s_hist[HIST];    // low16 = count in src, high16 = count in dst
    __shared__ unsigned s_cnt[2 * NN];   // per-row packed (cnt_in_src | cnt_in_dst<<16)
    __shared__ float    s_tab[NTAB * FF]; // table rows 0..15 (4 KB)

    const int b   = blockIdx.x;
    const int tid = threadIdx.x;

    // threads 0..127 own src rows, 128..255 own dst rows (coalesced id loads)
    const int my = (tid < NN) ? src[b * NN + tid] : dst[b * NN + (tid - NN)];
    const unsigned inc = (tid < NN) ? 1u : 0x10000u;
    const bool valid = (my >= 0) && (my < HIST);

    // stage hot table rows into LDS: 256 threads x 1 float4 = 4 KB, coalesced
    ((float4*)s_tab)[tid] = ((const float4*)table)[tid];

    #pragma unroll
    for (int i = tid; i < HIST; i += 256) s_hist[i] = 0u;
    __syncthreads();

    if (valid) atomicAdd(&s_hist[my], inc);
    __syncthreads();

    // src row: low=src_in_src, high=src_in_dst; dst row: low=dst_in_src, high=dst_in_dst.
    // Emit computes table[lo]+table[hi] -- symmetric in (lo,hi).
    s_cnt[tid] = valid ? s_hist[my] : 0u;
    __syncthreads();

    // ---- emit: out_row = table[c0] + table[c1]; each wave stores 1 KB contiguous ----
    const int g4 = tid & 15;        // float4 lane within a 64-float row
    const int n0 = tid >> 4;        // 0..15
    const float4* __restrict__ tab4 = (const float4*)table;
    float4* out_src = (float4*)out + (size_t)b * (NN * FF / 4);
    float4* out_dst = out_src + (size_t)BATCH * (NN * FF / 4);

    #pragma unroll
    for (int n = n0; n < NN; n += 16) {
        {
            const unsigned h  = s_cnt[n];
            const unsigned c0 = h & 0xffffu;
            const unsigned c1 = h >> 16;
            float4 v0 = *(const float4*)&s_tab[(c0 & (NTAB - 1)) * FF + g4 * 4];
            float4 v1 = *(const float4*)&s_tab[(c1 & (NTAB - 1)) * FF + g4 * 4];
            if (__builtin_expect((h & 0xfff0fff0u) != 0u, 0)) {
                // some count >= NTAB: take the exact global gather
                v0 = tab4[c0 * (FF / 4) + g4];
                v1 = tab4[c1 * (FF / 4) + g4];
            }
            float4 r;
            r.x = v0.x + v1.x; r.y = v0.y + v1.y;
            r.z = v0.z + v1.z; r.w = v0.w + v1.w;
            out_src[n * (FF / 4) + g4] = r;
        }
        {
            const unsigned h  = s_cnt[NN + n];
            const unsigned c0 = h & 0xffffu;
            const unsigned c1 = h >> 16;
            float4 v0 = *(const float4*)&s_tab[(c0 & (NTAB - 1)) * FF + g4 * 4];
            float4 v1 = *(const float4*)&s_tab[(c1 & (NTAB - 1)) * FF + g4 * 4];
            if (__builtin_expect((h & 0xfff0fff0u) != 0u, 0)) {
                v0 = tab4[c0 * (FF / 4) + g4];
                v1 = tab4[c1 * (FF / 4) + g4];
            }
            float4 r;
            r.x = v0.x + v1.x; r.y = v0.y + v1.y;
            r.z = v0.z + v1.z; r.w = v0.w + v1.w;
            out_dst[n * (FF / 4) + g4] = r;
        }
    }
}

extern "C" void kernel_launch(void* const* d_in, const int* in_sizes, int n_in,
                              void* d_out, int out_size, void* d_ws, size_t ws_size,
                              hipStream_t stream) {
    const int*   src = (const int*)d_in[0];
    const int*   dst = (const int*)d_in[1];
    const float* w1  = (const float*)d_in[2];
    const float* b1  = (const float*)d_in[3];
    const float* w2  = (const float*)d_in[4];
    const float* b2  = (const float*)d_in[5];
    float* out   = (float*)d_out;
    float* table = (float*)d_ws;   // 129*64*4 = 33,024 bytes

    build_table_kernel<<<NC, FF, 0, stream>>>(w1, b1, w2, b2, table);
    encode_kernel<<<BATCH, 256, 0, stream>>>(src, dst, table, out);
}